// Round 1
// baseline (352.652 us; speedup 1.0000x reference)
//
#include <hip/hip_runtime.h>

// Focal loss (prob-space) over dense [B,V] fp32 with ragged one-hot targets.
// Strategy: streaming t=0 pass + sparse correction at target indices.
#define NT 256
#define NB_MAIN 2048
#define B_ 2048
#define V_ 32000
#define T_ 20
#define NB_CORR ((B_ * T_ + NT - 1) / NT)  // 160

__device__ __forceinline__ float clip_p(float p) {
    // reference: clip(p, 1e-8, 1.0 - 1e-8); note (float)(1.0-1e-8) == 1.0f,
    // and src < 1.0 strictly, so upper clip is a no-op — kept for fidelity.
    return fminf(fmaxf(p, 1e-8f), 0.99999999f);
}

// t = 0 contribution: alpha_t = 0.75, p_t = 1-p -> 0.75 * p^2 * (-log(1-p))
__device__ __forceinline__ float loss_t0(float pc) {
    float om = 1.0f - pc;             // same fp32 rounding as reference's (1 - prob)
    return 0.75f * pc * pc * (-logf(om));
}

// t = 1 contribution: alpha_t = 0.25, p_t = p -> 0.25 * (1-p)^2 * (-log p)
__device__ __forceinline__ float loss_t1(float pc) {
    float om = 1.0f - pc;
    return 0.25f * om * om * (-logf(pc));
}

__device__ __forceinline__ double block_reduce_f64(double v) {
    #pragma unroll
    for (int off = 32; off > 0; off >>= 1) v += __shfl_down(v, off, 64);
    __shared__ double lds[NT / 64];
    int lane = threadIdx.x & 63;
    int wid  = threadIdx.x >> 6;
    if (lane == 0) lds[wid] = v;
    __syncthreads();
    double s = 0.0;
    if (threadIdx.x == 0) {
        #pragma unroll
        for (int w = 0; w < NT / 64; ++w) s += lds[w];
    }
    return s;
}

// Pass 1: sum loss_t0 over ALL elements (as if no element is a target).
__global__ __launch_bounds__(NT) void focal_main(const float* __restrict__ src,
                                                 double* __restrict__ part) {
    const long n4 = (long)B_ * V_ / 4;  // 16,384,000 — exact
    const long stride = (long)gridDim.x * NT;
    long i = (long)blockIdx.x * NT + threadIdx.x;
    const float4* s4 = (const float4*)src;
    double acc = 0.0;
    for (; i < n4; i += stride) {
        float4 v = s4[i];
        // fp32 partial of 4 terms (each ~O(1)), then exact add into double.
        float a = loss_t0(clip_p(v.x)) + loss_t0(clip_p(v.y)) +
                  loss_t0(clip_p(v.z)) + loss_t0(clip_p(v.w));
        acc += (double)a;
    }
    double s = block_reduce_f64(acc);
    if (threadIdx.x == 0) part[blockIdx.x] = s;
}

// Pass 2: for each unique (row, tgt) pair, replace t0 term with t1 term.
// Dedupe = first-occurrence wins (matches .at[rows,tgt].set(1.0) semantics).
__global__ __launch_bounds__(NT) void focal_corr(const float* __restrict__ src,
                                                 const int* __restrict__ tgt,
                                                 double* __restrict__ part) {
    int gid = blockIdx.x * NT + threadIdx.x;
    double acc = 0.0;
    if (gid < B_ * T_) {
        int row = gid / T_;
        int t   = gid - row * T_;
        const int* trow = tgt + row * T_;
        int idx = trow[t];
        bool first = true;
        for (int u = 0; u < t; ++u)
            if (trow[u] == idx) first = false;
        if (first && idx >= 0 && idx < V_) {
            float pc = clip_p(src[(long)row * V_ + idx]);
            acc = (double)(loss_t1(pc) - loss_t0(pc));
        }
    }
    double s = block_reduce_f64(acc);
    if (threadIdx.x == 0) part[NB_MAIN + blockIdx.x] = s;
}

// Pass 3: deterministic final reduction of all partials -> fp32 scalar.
__global__ __launch_bounds__(NT) void focal_final(const double* __restrict__ part,
                                                  float* __restrict__ out) {
    const int n = NB_MAIN + NB_CORR;
    double acc = 0.0;
    for (int i = threadIdx.x; i < n; i += NT) acc += part[i];
    double s = block_reduce_f64(acc);
    if (threadIdx.x == 0) out[0] = (float)s;
}

extern "C" void kernel_launch(void* const* d_in, const int* in_sizes, int n_in,
                              void* d_out, int out_size, void* d_ws, size_t ws_size,
                              hipStream_t stream) {
    const float* src = (const float*)d_in[0];
    const int*   tgt = (const int*)d_in[1];
    float*       out = (float*)d_out;
    double*      part = (double*)d_ws;  // NB_MAIN + NB_CORR doubles (~17.7 KB)

    focal_main<<<NB_MAIN, NT, 0, stream>>>(src, part);
    focal_corr<<<NB_CORR, NT, 0, stream>>>(src, tgt, part);
    focal_final<<<1, NT, 0, stream>>>(part, out);
}

// Round 3
// 351.230 us; speedup vs baseline: 1.0041x; 1.0041x over previous
//
#include <hip/hip_runtime.h>

// Focal loss (prob-space) over dense [B,V] fp32 with ragged one-hot targets.
// Streaming t=0 pass (memory-bound) + sparse correction at target indices.
// Fast hardware log2 (v_log_f32) with ln2 folded into constants; error
// analysis: sum drift << 1 ulp of the ~3e7 fp32 output.
#define NT 256
#define NB_MAIN 2048
#define B_ 2048
#define V_ 32000
#define T_ 20
#define NB_CORR ((B_ * T_ + NT - 1) / NT)  // 160

__device__ __forceinline__ float clip_p(float p) {
    // reference clip(p, 1e-8, 1-1e-8); fp32(1-1e-8)==1.0f and src<1, so
    // the upper clip is a no-op.
    return fmaxf(p, 1e-8f);
}

// t=0: 0.75 * p^2 * (-ln(1-p)) = C0 * p^2 * log2(1-p), C0 = -0.75*ln2
__device__ __forceinline__ float loss_t0(float pc) {
    float om = 1.0f - pc;
    return -0.51986038542f * pc * pc * __builtin_amdgcn_logf(om);
}

// t=1: 0.25 * (1-p)^2 * (-ln p) = C1 * (1-p)^2 * log2(p), C1 = -0.25*ln2
__device__ __forceinline__ float loss_t1(float pc) {
    float om = 1.0f - pc;
    return -0.17328679514f * om * om * __builtin_amdgcn_logf(pc);
}

__device__ __forceinline__ double block_reduce_f64(double v) {
    #pragma unroll
    for (int off = 32; off > 0; off >>= 1) v += __shfl_down(v, off, 64);
    __shared__ double lds[NT / 64];
    int lane = threadIdx.x & 63;
    int wid  = threadIdx.x >> 6;
    if (lane == 0) lds[wid] = v;
    __syncthreads();
    double s = 0.0;
    if (threadIdx.x == 0) {
        #pragma unroll
        for (int w = 0; w < NT / 64; ++w) s += lds[w];
    }
    return s;
}

// Pass 1: sum loss_t0 over ALL elements (as if nothing is a target).
__global__ __launch_bounds__(NT) void focal_main(const float* __restrict__ src,
                                                 double* __restrict__ part) {
    const long n4 = (long)B_ * V_ / 4;  // 16,384,000 exact
    const long stride = (long)gridDim.x * NT;
    long i = (long)blockIdx.x * NT + threadIdx.x;
    const float4* s4 = (const float4*)src;
    double acc = 0.0;
    for (; i < n4; i += stride) {
        float4 v = s4[i];
        float a = loss_t0(clip_p(v.x)) + loss_t0(clip_p(v.y)) +
                  loss_t0(clip_p(v.z)) + loss_t0(clip_p(v.w));
        acc += (double)a;
    }
    double s = block_reduce_f64(acc);
    if (threadIdx.x == 0) part[blockIdx.x] = s;
}

// Pass 2: for each unique (row, tgt) pair, swap the t0 term for the t1 term.
// Dedupe = first occurrence (matches .at[rows,tgt].set(1.0) semantics);
// loss_t0 here is the same inlined formula as pass 1 so it cancels exactly.
__global__ __launch_bounds__(NT) void focal_corr(const float* __restrict__ src,
                                                 const int* __restrict__ tgt,
                                                 double* __restrict__ part) {
    int gid = blockIdx.x * NT + threadIdx.x;
    double acc = 0.0;
    if (gid < B_ * T_) {
        int row = gid / T_;
        int t   = gid - row * T_;
        const int* trow = tgt + row * T_;
        int idx = trow[t];
        bool first = true;
        for (int u = 0; u < t; ++u)
            if (trow[u] == idx) first = false;
        if (first && idx >= 0 && idx < V_) {
            float pc = clip_p(src[(long)row * V_ + idx]);
            acc = (double)(loss_t1(pc) - loss_t0(pc));
        }
    }
    double s = block_reduce_f64(acc);
    if (threadIdx.x == 0) part[NB_MAIN + blockIdx.x] = s;
}

// Pass 3: deterministic final reduction of partials -> fp32 scalar.
__global__ __launch_bounds__(NT) void focal_final(const double* __restrict__ part,
                                                  float* __restrict__ out) {
    const int n = NB_MAIN + NB_CORR;
    double acc = 0.0;
    for (int i = threadIdx.x; i < n; i += NT) acc += part[i];
    double s = block_reduce_f64(acc);
    if (threadIdx.x == 0) out[0] = (float)s;
}

extern "C" void kernel_launch(void* const* d_in, const int* in_sizes, int n_in,
                              void* d_out, int out_size, void* d_ws, size_t ws_size,
                              hipStream_t stream) {
    const float* src = (const float*)d_in[0];
    const int*   tgt = (const int*)d_in[1];
    float*       out = (float*)d_out;
    double*      part = (double*)d_ws;  // NB_MAIN + NB_CORR doubles (~17.7 KB)

    focal_main<<<NB_MAIN, NT, 0, stream>>>(src, part);
    focal_corr<<<NB_CORR, NT, 0, stream>>>(src, tgt, part);
    focal_final<<<1, NT, 0, stream>>>(part, out);
}

// Round 4
// 350.217 us; speedup vs baseline: 1.0070x; 1.0029x over previous
//
#include <hip/hip_runtime.h>

// Focal loss (prob-space) over dense [B,V] fp32 with ragged one-hot targets.
// Fused: streaming t=0 sum + per-row sparse correction in ONE kernel
// (block b owns row b's 20 target pairs; gather latency hides under the
// ~31 streaming iterations). Then one tiny final reduction.
#define NT 256
#define NB 2048            // == B_: one block per row for the correction
#define B_ 2048
#define V_ 32000
#define T_ 20

__device__ __forceinline__ float clip_p(float p) {
    // reference clip(p, 1e-8, 1-1e-8); fp32(1-1e-8)==1.0f and src<1 ->
    // upper clip is a no-op.
    return fmaxf(p, 1e-8f);
}

// t=0: 0.75 * p^2 * (-ln(1-p)) = C0 * p^2 * log2(1-p), C0 = -0.75*ln2
__device__ __forceinline__ float loss_t0(float pc) {
    float om = 1.0f - pc;
    return -0.51986038542f * pc * pc * __builtin_amdgcn_logf(om);
}

// t=1: 0.25 * (1-p)^2 * (-ln p) = C1 * (1-p)^2 * log2(p), C1 = -0.25*ln2
__device__ __forceinline__ float loss_t1(float pc) {
    float om = 1.0f - pc;
    return -0.17328679514f * om * om * __builtin_amdgcn_logf(pc);
}

__device__ __forceinline__ double block_reduce_f64(double v) {
    #pragma unroll
    for (int off = 32; off > 0; off >>= 1) v += __shfl_down(v, off, 64);
    __shared__ double lds[NT / 64];
    int lane = threadIdx.x & 63;
    int wid  = threadIdx.x >> 6;
    if (lane == 0) lds[wid] = v;
    __syncthreads();
    double s = 0.0;
    if (threadIdx.x == 0) {
        #pragma unroll
        for (int w = 0; w < NT / 64; ++w) s += lds[w];
    }
    return s;
}

// Fused pass: grid-stride t=0 sum over all elements, plus block b swaps in
// the t=1 term for row b's unique target indices (first-occurrence dedupe,
// matching .at[rows,tgt].set(1.0)). Same inlined loss_t0 both places so the
// correction cancels the streaming term exactly.
__global__ __launch_bounds__(NT) void focal_fused(const float* __restrict__ src,
                                                  const int* __restrict__ tgt,
                                                  double* __restrict__ part) {
    double acc = 0.0;

    // --- sparse correction: thread t (< T_) handles (row=blockIdx.x, t) ---
    if (threadIdx.x < T_) {
        int row = blockIdx.x;
        const int* trow = tgt + row * T_;
        int t   = threadIdx.x;
        int idx = trow[t];
        bool first = true;
        for (int u = 0; u < t; ++u)
            if (trow[u] == idx) first = false;
        if (first && idx >= 0 && idx < V_) {
            float pc = clip_p(src[(long)row * V_ + idx]);
            acc = (double)(loss_t1(pc) - loss_t0(pc));
        }
    }

    // --- streaming t=0 sum (memory-bound) ---
    const long n4 = (long)B_ * V_ / 4;  // 16,384,000 exact
    const long stride = (long)NB * NT;
    long i = (long)blockIdx.x * NT + threadIdx.x;
    const float4* s4 = (const float4*)src;
    for (; i < n4; i += stride) {
        float4 v = s4[i];
        float a = loss_t0(clip_p(v.x)) + loss_t0(clip_p(v.y)) +
                  loss_t0(clip_p(v.z)) + loss_t0(clip_p(v.w));
        acc += (double)a;
    }

    double s = block_reduce_f64(acc);
    if (threadIdx.x == 0) part[blockIdx.x] = s;
}

// Final: deterministic reduction of 2048 partials -> fp32 scalar.
__global__ __launch_bounds__(NT) void focal_final(const double* __restrict__ part,
                                                  float* __restrict__ out) {
    double acc = 0.0;
    for (int i = threadIdx.x; i < NB; i += NT) acc += part[i];
    double s = block_reduce_f64(acc);
    if (threadIdx.x == 0) out[0] = (float)s;
}

extern "C" void kernel_launch(void* const* d_in, const int* in_sizes, int n_in,
                              void* d_out, int out_size, void* d_ws, size_t ws_size,
                              hipStream_t stream) {
    const float* src = (const float*)d_in[0];
    const int*   tgt = (const int*)d_in[1];
    float*       out = (float*)d_out;
    double*      part = (double*)d_ws;  // NB doubles (16 KB)

    focal_fused<<<NB, NT, 0, stream>>>(src, tgt, part);
    focal_final<<<1, NT, 0, stream>>>(part, out);
}